// Round 17
// baseline (56.668 us; speedup 1.0000x reference)
//
#include <hip/hip_runtime.h>
#include <hip/hip_bf16.h>

#define SLEN 8192
#define EDIM 1024
#define NB2  512   // attn_wv blocks; 16 positions per block (2 per wave, 8 waves)

typedef float f4 __attribute__((ext_vector_type(4)));

// ---------------- helpers ----------------

__device__ inline float2 blockSum512_2(float2 v, float2* lds) {
#pragma unroll
    for (int off = 32; off; off >>= 1) {
        v.x += __shfl_xor(v.x, off);
        v.y += __shfl_xor(v.y, off);
    }
    int w = threadIdx.x >> 6, ln = threadIdx.x & 63;
    __syncthreads();
    if (ln == 0) lds[w] = v;
    __syncthreads();
    float2 s = {0.f, 0.f};
#pragma unroll
    for (int i = 0; i < 8; ++i) { s.x += lds[i].x; s.y += lds[i].y; }
    return s;
}

__device__ inline float2 blockSum1024_2(float2 v, float2* lds) {
#pragma unroll
    for (int off = 32; off; off >>= 1) {
        v.x += __shfl_xor(v.x, off);
        v.y += __shfl_xor(v.y, off);
    }
    int w = threadIdx.x >> 6, ln = threadIdx.x & 63;
    __syncthreads();
    if (ln == 0) lds[w] = v;
    __syncthreads();
    float2 s = {0.f, 0.f};
#pragma unroll
    for (int i = 0; i < 16; ++i) { s.x += lds[i].x; s.y += lds[i].y; }
    return s;
}

// ---------------- QKV GEMV (split-K partials) ----------------
// grid (12, 16), block 256
__global__ __launch_bounds__(256) void qkv_partial(
    const float* __restrict__ Wq, const float* __restrict__ Wk,
    const float* __restrict__ Wv, const float* __restrict__ x,
    float* __restrict__ part) {
    int cg_ = blockIdx.x;
    int m = cg_ >> 2;
    const float* W = (m == 0) ? Wq : ((m == 1) ? Wk : Wv);
    int col = (cg_ & 3) * 256 + threadIdx.x;
    int r0 = blockIdx.y * 64;
    float acc = 0.f;
#pragma unroll 16
    for (int r = 0; r < 64; ++r)
        acc = fmaf(x[r0 + r], W[(r0 + r) * EDIM + col], acc);
    part[((size_t)m * 16 + blockIdx.y) * EDIM + col] = acc;
}

// ---------------- cache shift as COPY-SHAPED streams ----------------
// grid 1024, block 512 (8 waves, 2 positions/wave; 16 positions/block).
// Even blocks: V-half copy + per-position nz flag (1R + 1W stream).
// Odd blocks:  K-half copy + per-position per-head q.k scores (1R + 1W stream).
__global__ __launch_bounds__(512) void attn_copy(
    const float* __restrict__ cache,   // [2, S, 1024]
    const float* __restrict__ qkvp,    // [48][1024] (q:0-15, k:16-31, v:32-47)
    const float* __restrict__ bq, const float* __restrict__ bk,
    const float* __restrict__ bv,
    float* __restrict__ nv, float* __restrict__ nk,
    float* __restrict__ flag, float* __restrict__ score) {
    __shared__ float qs_l[1024];
    __shared__ float aux[1024];   // vi (block 1022) / ki (block 1023)
    int b = blockIdx.x, tid = threadIdx.x;
    int w = tid >> 6, ld = tid & 63;
    int c = b >> 1;
    bool isK = (b & 1) != 0;
    int s0 = c * 16 + w * 2;

    if (isK) {
        // rebuild qs = (x@Wq + bq)/8 from partials (L2-hot)
#pragma unroll
        for (int j = 0; j < 2; ++j) {
            int i = tid + 512 * j;
            float v = bq[i];
#pragma unroll
            for (int sl = 0; sl < 16; ++sl) v += qkvp[sl * EDIM + i];
            qs_l[i] = v * 0.125f;
        }
        if (b == 1023) {   // rebuild ki (k row for s = SLEN-1)
#pragma unroll
            for (int j = 0; j < 2; ++j) {
                int i = tid + 512 * j;
                float v = bk[i];
#pragma unroll
                for (int sl = 0; sl < 16; ++sl) v += qkvp[(16 + sl) * EDIM + i];
                aux[i] = v;
            }
        }
    } else if (b == 1022) {   // rebuild vi (v row for s = SLEN-1)
#pragma unroll
        for (int j = 0; j < 2; ++j) {
            int i = tid + 512 * j;
            float v = bv[i];
#pragma unroll
            for (int sl = 0; sl < 16; ++sl) v += qkvp[(32 + sl) * EDIM + i];
            aux[i] = v;
        }
    }
    __syncthreads();

    if (!isK) {
        // ---- V-half: pure copy + nz flag ----
        f4 vv[2][4];
#pragma unroll
        for (int p = 0; p < 2; ++p) {
            int s = s0 + p;
            const float* src = (s < SLEN - 1) ? cache + (size_t)(s + 1) * EDIM
                                              : aux;
#pragma unroll
            for (int it = 0; it < 4; ++it)
                vv[p][it] = *(const f4*)(src + it * 256 + ld * 4);
        }
#pragma unroll
        for (int p = 0; p < 2; ++p) {
            int s = s0 + p;
            unsigned nzb = 0u;
#pragma unroll
            for (int it = 0; it < 4; ++it) {
                *(f4*)(nv + (size_t)s * EDIM + it * 256 + ld * 4) = vv[p][it];
                nzb |= __float_as_uint(vv[p][it].x) | __float_as_uint(vv[p][it].y) |
                       __float_as_uint(vv[p][it].z) | __float_as_uint(vv[p][it].w);
            }
            bool anynz = (__ballot(nzb != 0u) != 0ull);
            if (ld == 0) flag[s] = anynz ? 1.f : 0.f;
        }
    } else {
        // ---- K-half: copy + per-head scores ----
        f4 q4[4];
#pragma unroll
        for (int it = 0; it < 4; ++it)
            q4[it] = *(const f4*)&qs_l[it * 256 + ld * 4];
        f4 kv[2][4];
#pragma unroll
        for (int p = 0; p < 2; ++p) {
            int s = s0 + p;
            const float* src = (s < SLEN - 1) ? cache + (size_t)(SLEN + s + 1) * EDIM
                                              : aux;
#pragma unroll
            for (int it = 0; it < 4; ++it)
                kv[p][it] = *(const f4*)(src + it * 256 + ld * 4);
        }
#pragma unroll
        for (int p = 0; p < 2; ++p) {
            int s = s0 + p;
#pragma unroll
            for (int it = 0; it < 4; ++it) {
                *(f4*)(nk + (size_t)s * EDIM + it * 256 + ld * 4) = kv[p][it];
                float d = q4[it].x * kv[p][it].x + q4[it].y * kv[p][it].y +
                          q4[it].z * kv[p][it].z + q4[it].w * kv[p][it].w;
                d += __shfl_xor(d, 1);
                d += __shfl_xor(d, 2);
                d += __shfl_xor(d, 4);
                d += __shfl_xor(d, 8);
                if ((ld & 15) == 0) score[s * 16 + it * 4 + (ld >> 4)] = d;
            }
        }
    }
}

// ---------------- weighted-V accumulation (reads L3-resident nv) ----------------
// grid NB2=512, block 512 (8 waves, 2 positions/wave). No-max softmax:
// wg = flag ? exp(score) : 0; plain linear sums -> block partial via LDS merge.
__global__ __launch_bounds__(512) void attn_wv(
    const float* __restrict__ nv, const float* __restrict__ flag,
    const float* __restrict__ score,
    float* __restrict__ l2, float* __restrict__ acc2) {
    __shared__ float sw[8][16];
    __shared__ float sacc[8][16][64];
    int tid = threadIdx.x;
    int w = tid >> 6, ld = tid & 63;
    int s0 = blockIdx.x * 16 + w * 2;

    float wgsum[4];
    f4 acc[4];
#pragma unroll
    for (int it = 0; it < 4; ++it) {
        wgsum[it] = 0.f;
        acc[it] = (f4){0.f, 0.f, 0.f, 0.f};
    }
#pragma unroll
    for (int p = 0; p < 2; ++p) {
        int s = s0 + p;
        f4 vv[4];
#pragma unroll
        for (int it = 0; it < 4; ++it)
            vv[it] = *(const f4*)(nv + (size_t)s * EDIM + it * 256 + ld * 4);
        float fl = flag[s];
#pragma unroll
        for (int it = 0; it < 4; ++it) {
            int h = it * 4 + (ld >> 4);
            float wg = (fl != 0.f) ? __expf(score[s * 16 + h]) : 0.f;
            wgsum[it] += wg;
            acc[it].x = fmaf(wg, vv[it].x, acc[it].x);
            acc[it].y = fmaf(wg, vv[it].y, acc[it].y);
            acc[it].z = fmaf(wg, vv[it].z, acc[it].z);
            acc[it].w = fmaf(wg, vv[it].w, acc[it].w);
        }
    }
    if ((ld & 15) == 0) {
#pragma unroll
        for (int it = 0; it < 4; ++it) sw[w][it * 4 + (ld >> 4)] = wgsum[it];
    }
#pragma unroll
    for (int it = 0; it < 4; ++it) {
        int h = it * 4 + (ld >> 4);
        *(f4*)&sacc[w][h][(ld & 15) * 4] = acc[it];
    }
    __syncthreads();

    // wave w owns heads 2w, 2w+1: sum across 8 waves; write block partial
#pragma unroll
    for (int j = 0; j < 2; ++j) {
        int h = 2 * w + j;
        float a = 0.f;
#pragma unroll
        for (int ww = 0; ww < 8; ++ww) a += sacc[ww][h][ld];
        acc2[(size_t)blockIdx.x * 1024 + h * 64 + ld] = a;
        if (ld == 0) {
            float l = 0.f;
#pragma unroll
            for (int ww = 0; ww < 8; ++ww) l += sw[ww][h];
            l2[blockIdx.x * 16 + h] = l;
        }
    }
}

// level-1 linear reduce: grid (16 col-chunks, 8 p-groups), block 256 (4 waves).
__global__ __launch_bounds__(256) void attn_red(
    const float* __restrict__ l2, const float* __restrict__ acc2,
    float* __restrict__ l3g, float* __restrict__ acc3) {
    __shared__ float sA[4][64];
    __shared__ float sLl[4][16];
    int cx = blockIdx.x, g = blockIdx.y;
    int t = threadIdx.x, w = t >> 6, ld = t & 63;
    int p0 = g * 64 + w * 16;
    float a = 0.f;
#pragma unroll
    for (int i = 0; i < 16; ++i)
        a += acc2[(size_t)(p0 + i) * 1024 + cx * 64 + ld];
    sA[w][ld] = a;
    if (cx == 0 && ld < 16) {
        float l = 0.f;
#pragma unroll
        for (int i = 0; i < 16; ++i) l += l2[(p0 + i) * 16 + ld];
        sLl[w][ld] = l;
    }
    __syncthreads();
    if (w == 0) {
        acc3[(size_t)g * 1024 + cx * 64 + ld] =
            sA[0][ld] + sA[1][ld] + sA[2][ld] + sA[3][ld];
        if (cx == 0 && ld < 16)
            l3g[g * 16 + ld] = sLl[0][ld] + sLl[1][ld] + sLl[2][ld] + sLl[3][ld];
    }
}

// Wo GEMV; prologue merges 8 group sums + divide.
// grid (4, 16), block 512 (8 waves, 2-way row split). blockIdx.y = head.
__global__ __launch_bounds__(512) void gemv_wo(
    const float* __restrict__ Wo,
    const float* __restrict__ l3g, const float* __restrict__ acc3,
    float* __restrict__ part) {
    __shared__ float vals[64];
    __shared__ float sred[2][256];
    int by = blockIdx.y;
    int t = threadIdx.x;
    if (t < 64) {
        float a = 0.f, L = 0.f;
#pragma unroll
        for (int g = 0; g < 8; ++g) {
            a += acc3[(size_t)g * 1024 + by * 64 + t];
            L += l3g[g * 16 + by];
        }
        vals[t] = a / L;
    }
    __syncthreads();
    int half = t >> 8, tc = t & 255;
    int col = blockIdx.x * 256 + tc;
    float acc = 0.f;
#pragma unroll 16
    for (int r = 0; r < 32; ++r)
        acc = fmaf(vals[half * 32 + r],
                   Wo[(size_t)(by * 64 + half * 32 + r) * EDIM + col], acc);
    sred[half][tc] = acc;
    __syncthreads();
    if (t < 256)
        part[(size_t)by * EDIM + blockIdx.x * 256 + t] = sred[0][t] + sred[1][t];
}

// W1 GEMV with fused residual+LN1 prologue. grid (4,16), block 512.
__global__ __launch_bounds__(512) void gemv_w1(
    const float* __restrict__ W1, const float* __restrict__ gp1,
    const float* __restrict__ bo, const float* __restrict__ x,
    const float* __restrict__ ln1s, const float* __restrict__ ln1b,
    float* __restrict__ h1, float* __restrict__ part) {
    __shared__ float r_l[1024];
    __shared__ float2 red[8];
    __shared__ float vals[64];
    __shared__ float sred[2][256];
    int t = threadIdx.x;
    float2 ss = {0.f, 0.f};
#pragma unroll
    for (int j = 0; j < 2; ++j) {
        int i = t + 512 * j;
        float v = x[i] + bo[i];
#pragma unroll
        for (int sl = 0; sl < 16; ++sl) v += gp1[(size_t)sl * EDIM + i];
        r_l[i] = v;
        ss.x += v; ss.y += v * v;
    }
    float2 s = blockSum512_2(ss, red);
    float mean = s.x * (1.f / 1024.f);
    float var = s.y * (1.f / 1024.f) - mean * mean;
    float rstd = rsqrtf(var + 1e-6f);
    int by = blockIdx.y;
    if (t < 64) {
        int row = by * 64 + t;
        float hv = (r_l[row] - mean) * rstd * ln1s[row] + ln1b[row];
        vals[t] = hv;
        if (blockIdx.x == 0) h1[row] = hv;
    }
    __syncthreads();
    int half = t >> 8, tc = t & 255;
    int col = blockIdx.x * 256 + tc;
    float acc = 0.f;
#pragma unroll 16
    for (int r = 0; r < 32; ++r)
        acc = fmaf(vals[half * 32 + r],
                   W1[(size_t)(by * 64 + half * 32 + r) * EDIM + col], acc);
    sred[half][tc] = acc;
    __syncthreads();
    if (t < 256)
        part[(size_t)by * EDIM + blockIdx.x * 256 + t] = sred[0][t] + sred[1][t];
}

// W2 GEMV with fused (bias + sum-partials + ReLU) prologue. grid (4,16), block 512.
__global__ __launch_bounds__(512) void gemv_w2(
    const float* __restrict__ W2, const float* __restrict__ gp2,
    const float* __restrict__ b1, float* __restrict__ part) {
    __shared__ float vals[64];
    __shared__ float sred[2][256];
    int by = blockIdx.y;
    int t = threadIdx.x;
    if (t < 64) {
        int r = by * 64 + t;
        float v = b1[r];
#pragma unroll
        for (int sl = 0; sl < 16; ++sl) v += gp2[(size_t)sl * EDIM + r];
        vals[t] = fmaxf(v, 0.f);
    }
    __syncthreads();
    int half = t >> 8, tc = t & 255;
    int col = blockIdx.x * 256 + tc;
    float acc = 0.f;
#pragma unroll 16
    for (int r = 0; r < 32; ++r)
        acc = fmaf(vals[half * 32 + r],
                   W2[(size_t)(by * 64 + half * 32 + r) * EDIM + col], acc);
    sred[half][tc] = acc;
    __syncthreads();
    if (t < 256)
        part[(size_t)by * EDIM + blockIdx.x * 256 + t] = sred[0][t] + sred[1][t];
}

// final LN: 1 block 1024. r = h1 + b2 + sum partials; out = LN(r)*g + b
__global__ __launch_bounds__(1024) void combine_ln(
    const float* __restrict__ part, const float* __restrict__ bias,
    const float* __restrict__ resid, const float* __restrict__ g,
    const float* __restrict__ b, float* __restrict__ out) {
    __shared__ float2 lds[16];
    int t = threadIdx.x;
    float v = bias[t];
#pragma unroll
    for (int sl = 0; sl < 16; ++sl) v += part[(size_t)sl * EDIM + t];
    float r = resid[t] + v;
    float2 s = blockSum1024_2((float2){r, r * r}, lds);
    float mean = s.x * (1.f / 1024.f);
    float var = s.y * (1.f / 1024.f) - mean * mean;
    out[t] = (r - mean) * rsqrtf(var + 1e-6f) * g[t] + b[t];
}

// ---------------- launch ----------------
extern "C" void kernel_launch(void* const* d_in, const int* in_sizes, int n_in,
                              void* d_out, int out_size, void* d_ws, size_t ws_size,
                              hipStream_t stream) {
    const float* x     = (const float*)d_in[0];
    const float* cache = (const float*)d_in[1];
    const float* Wv    = (const float*)d_in[2];
    const float* bv    = (const float*)d_in[3];
    const float* Wq    = (const float*)d_in[4];
    const float* bq    = (const float*)d_in[5];
    const float* Wk    = (const float*)d_in[6];
    const float* bk    = (const float*)d_in[7];
    const float* Wo    = (const float*)d_in[8];
    const float* bo    = (const float*)d_in[9];
    const float* W1    = (const float*)d_in[10];
    const float* b1    = (const float*)d_in[11];
    const float* W2    = (const float*)d_in[12];
    const float* b2    = (const float*)d_in[13];
    const float* ln1s  = (const float*)d_in[14];
    const float* ln1b  = (const float*)d_in[15];
    const float* ln2s  = (const float*)d_in[16];
    const float* ln2b  = (const float*)d_in[17];

    float* out = (float*)d_out;
    float* nv = out + 1024;
    float* nk = out + 1024 + (size_t)SLEN * EDIM;

    float* w     = (float*)d_ws;
    float* qkvp  = w;                           // 48*1024
    float* flag  = qkvp + 48 * 1024;            // 8192
    float* score = flag + SLEN;                 // 8192*16
    float* l2    = score + (size_t)SLEN * 16;   // NB2*16
    float* acc2  = l2 + (size_t)NB2 * 16;       // NB2*1024
    float* l3g   = acc2 + (size_t)NB2 * 1024;   // 128
    float* acc3  = l3g + 128;                   // 8*1024
    float* gp1   = acc3 + 8 * 1024;             // 16*1024
    float* h1    = gp1 + 16 * 1024;             // 1024
    float* gp2   = h1 + 1024;                   // 16*1024
    float* gp3   = gp2 + 16 * 1024;             // 16*1024

    qkv_partial<<<dim3(12, 16), 256, 0, stream>>>(Wq, Wk, Wv, x, qkvp);
    attn_copy<<<1024, 512, 0, stream>>>(cache, qkvp, bq, bk, bv, nv, nk, flag, score);
    attn_wv<<<NB2, 512, 0, stream>>>(nv, flag, score, l2, acc2);
    attn_red<<<dim3(16, 8), 256, 0, stream>>>(l2, acc2, l3g, acc3);
    gemv_wo<<<dim3(4, 16), 512, 0, stream>>>(Wo, l3g, acc3, gp1);
    gemv_w1<<<dim3(4, 16), 512, 0, stream>>>(W1, gp1, bo, x, ln1s, ln1b, h1, gp2);
    gemv_w2<<<dim3(4, 16), 512, 0, stream>>>(W2, gp2, b1, gp3);
    combine_ln<<<1, 1024, 0, stream>>>(gp3, b2, h1, ln2s, ln2b, out);
}

// Round 18
// 52.071 us; speedup vs baseline: 1.0883x; 1.0883x over previous
//
#include <hip/hip_runtime.h>
#include <hip/hip_bf16.h>

#define SLEN 8192
#define EDIM 1024
#define NB2  512   // attn_copyV blocks; 16 positions per block (2 per wave, 8 waves)

typedef float f4 __attribute__((ext_vector_type(4)));

// ---------------- helpers ----------------

__device__ inline float2 blockSum512_2(float2 v, float2* lds) {
#pragma unroll
    for (int off = 32; off; off >>= 1) {
        v.x += __shfl_xor(v.x, off);
        v.y += __shfl_xor(v.y, off);
    }
    int w = threadIdx.x >> 6, ln = threadIdx.x & 63;
    __syncthreads();
    if (ln == 0) lds[w] = v;
    __syncthreads();
    float2 s = {0.f, 0.f};
#pragma unroll
    for (int i = 0; i < 8; ++i) { s.x += lds[i].x; s.y += lds[i].y; }
    return s;
}

__device__ inline float2 blockSum1024_2(float2 v, float2* lds) {
#pragma unroll
    for (int off = 32; off; off >>= 1) {
        v.x += __shfl_xor(v.x, off);
        v.y += __shfl_xor(v.y, off);
    }
    int w = threadIdx.x >> 6, ln = threadIdx.x & 63;
    __syncthreads();
    if (ln == 0) lds[w] = v;
    __syncthreads();
    float2 s = {0.f, 0.f};
#pragma unroll
    for (int i = 0; i < 16; ++i) { s.x += lds[i].x; s.y += lds[i].y; }
    return s;
}

// ---------------- QKV GEMV (split-K partials) ----------------
// grid (12, 16), block 256
__global__ __launch_bounds__(256) void qkv_partial(
    const float* __restrict__ Wq, const float* __restrict__ Wk,
    const float* __restrict__ Wv, const float* __restrict__ x,
    float* __restrict__ part) {
    int cg_ = blockIdx.x;
    int m = cg_ >> 2;
    const float* W = (m == 0) ? Wq : ((m == 1) ? Wk : Wv);
    int col = (cg_ & 3) * 256 + threadIdx.x;
    int r0 = blockIdx.y * 64;
    float acc = 0.f;
#pragma unroll 16
    for (int r = 0; r < 64; ++r)
        acc = fmaf(x[r0 + r], W[(r0 + r) * EDIM + col], acc);
    part[((size_t)m * 16 + blockIdx.y) * EDIM + col] = acc;
}

// ---------------- phase 1: K-half copy + scores (pure 1R+1W per block) ----------
// grid 512, block 512 (8 waves, 2 positions/wave).
__global__ __launch_bounds__(512) void attn_copyK(
    const float* __restrict__ cache,   // [2, S, 1024]
    const float* __restrict__ qkvp,    // [48][1024] (q:0-15, k:16-31, v:32-47)
    const float* __restrict__ bq, const float* __restrict__ bk,
    float* __restrict__ nk, float* __restrict__ score) {
    __shared__ float qs_l[1024];
    __shared__ float aux[1024];   // ki for the last block
    int tid = threadIdx.x;
    int w = tid >> 6, ld = tid & 63;
    int s0 = blockIdx.x * 16 + w * 2;

    // rebuild qs = (x@Wq + bq)/8 from partials (L2-hot)
#pragma unroll
    for (int j = 0; j < 2; ++j) {
        int i = tid + 512 * j;
        float v = bq[i];
#pragma unroll
        for (int sl = 0; sl < 16; ++sl) v += qkvp[sl * EDIM + i];
        qs_l[i] = v * 0.125f;
    }
    if (blockIdx.x == 511) {   // rebuild ki = x@Wk + bk
#pragma unroll
        for (int j = 0; j < 2; ++j) {
            int i = tid + 512 * j;
            float v = bk[i];
#pragma unroll
            for (int sl = 0; sl < 16; ++sl) v += qkvp[(16 + sl) * EDIM + i];
            aux[i] = v;
        }
    }
    __syncthreads();

    f4 q4[4];
#pragma unroll
    for (int it = 0; it < 4; ++it)
        q4[it] = *(const f4*)&qs_l[it * 256 + ld * 4];

    f4 kv[2][4];
#pragma unroll
    for (int p = 0; p < 2; ++p) {
        int s = s0 + p;
        const float* src = (s < SLEN - 1) ? cache + (size_t)(SLEN + s + 1) * EDIM
                                          : aux;
#pragma unroll
        for (int it = 0; it < 4; ++it)
            kv[p][it] = *(const f4*)(src + it * 256 + ld * 4);
    }
#pragma unroll
    for (int p = 0; p < 2; ++p) {
        int s = s0 + p;
#pragma unroll
        for (int it = 0; it < 4; ++it) {
            *(f4*)(nk + (size_t)s * EDIM + it * 256 + ld * 4) = kv[p][it];
            float d = q4[it].x * kv[p][it].x + q4[it].y * kv[p][it].y +
                      q4[it].z * kv[p][it].z + q4[it].w * kv[p][it].w;
            d += __shfl_xor(d, 1);
            d += __shfl_xor(d, 2);
            d += __shfl_xor(d, 4);
            d += __shfl_xor(d, 8);
            if ((ld & 15) == 0) score[s * 16 + it * 4 + (ld >> 4)] = d;
        }
    }
}

// ---------------- phase 2: V-half copy + nz + weighted accumulation ------------
// grid NB2=512, block 512. Scores from L2; no-max softmax (validated R9/R10).
__global__ __launch_bounds__(512) void attn_copyV(
    const float* __restrict__ cache,   // [2, S, 1024]
    const float* __restrict__ qkvp,
    const float* __restrict__ bv,
    const float* __restrict__ score,
    float* __restrict__ nv,
    float* __restrict__ l2, float* __restrict__ acc2) {
    __shared__ float sw[8][16];
    __shared__ float sacc[8][16][64];  // 32 KB; first 1024 floats alias vi
    float* aux = &sacc[0][0][0];
    int tid = threadIdx.x;
    int w = tid >> 6, ld = tid & 63;
    int s0 = blockIdx.x * 16 + w * 2;

    if (blockIdx.x == NB2 - 1) {   // rebuild vi = x@Wv + bv
#pragma unroll
        for (int j = 0; j < 2; ++j) {
            int i = tid + 512 * j;
            float v = bv[i];
#pragma unroll
            for (int sl = 0; sl < 16; ++sl) v += qkvp[(32 + sl) * EDIM + i];
            aux[i] = v;
        }
    }
    __syncthreads();

    f4 vv[2][4];
#pragma unroll
    for (int p = 0; p < 2; ++p) {
        int s = s0 + p;
        const float* src = (s < SLEN - 1) ? cache + (size_t)(s + 1) * EDIM
                                          : aux;
#pragma unroll
        for (int it = 0; it < 4; ++it)
            vv[p][it] = *(const f4*)(src + it * 256 + ld * 4);
    }
#pragma unroll
    for (int p = 0; p < 2; ++p) {
        int s = s0 + p;
#pragma unroll
        for (int it = 0; it < 4; ++it)
            *(f4*)(nv + (size_t)s * EDIM + it * 256 + ld * 4) = vv[p][it];
    }

    float wgsum[4];
    f4 acc[4];
#pragma unroll
    for (int it = 0; it < 4; ++it) {
        wgsum[it] = 0.f;
        acc[it] = (f4){0.f, 0.f, 0.f, 0.f};
    }
#pragma unroll
    for (int p = 0; p < 2; ++p) {
        int s = s0 + p;
        unsigned nzb = 0u;
#pragma unroll
        for (int it = 0; it < 4; ++it)
            nzb |= __float_as_uint(vv[p][it].x) | __float_as_uint(vv[p][it].y) |
                   __float_as_uint(vv[p][it].z) | __float_as_uint(vv[p][it].w);
        bool allz = (__ballot(nzb != 0u) == 0ull);
#pragma unroll
        for (int it = 0; it < 4; ++it) {
            int h = it * 4 + (ld >> 4);
            float wg = allz ? 0.f : __expf(score[s * 16 + h]);
            wgsum[it] += wg;
            acc[it].x = fmaf(wg, vv[p][it].x, acc[it].x);
            acc[it].y = fmaf(wg, vv[p][it].y, acc[it].y);
            acc[it].z = fmaf(wg, vv[p][it].z, acc[it].z);
            acc[it].w = fmaf(wg, vv[p][it].w, acc[it].w);
        }
    }
    if ((ld & 15) == 0) {
#pragma unroll
        for (int it = 0; it < 4; ++it) sw[w][it * 4 + (ld >> 4)] = wgsum[it];
    }
    __syncthreads();   // all aux reads complete before sacc overwrite

#pragma unroll
    for (int it = 0; it < 4; ++it) {
        int h = it * 4 + (ld >> 4);
        *(f4*)&sacc[w][h][(ld & 15) * 4] = acc[it];
    }
    __syncthreads();

    // wave w owns heads 2w, 2w+1: sum across 8 waves; write block partial
#pragma unroll
    for (int j = 0; j < 2; ++j) {
        int h = 2 * w + j;
        float a = 0.f;
#pragma unroll
        for (int ww = 0; ww < 8; ++ww) a += sacc[ww][h][ld];
        acc2[(size_t)blockIdx.x * 1024 + h * 64 + ld] = a;
        if (ld == 0) {
            float l = 0.f;
#pragma unroll
            for (int ww = 0; ww < 8; ++ww) l += sw[ww][h];
            l2[blockIdx.x * 16 + h] = l;
        }
    }
}

// level-1 linear reduce: grid (16 col-chunks, 8 p-groups), block 256 (4 waves).
__global__ __launch_bounds__(256) void attn_red(
    const float* __restrict__ l2, const float* __restrict__ acc2,
    float* __restrict__ l3g, float* __restrict__ acc3) {
    __shared__ float sA[4][64];
    __shared__ float sLl[4][16];
    int cx = blockIdx.x, g = blockIdx.y;
    int t = threadIdx.x, w = t >> 6, ld = t & 63;
    int p0 = g * 64 + w * 16;
    float a = 0.f;
#pragma unroll
    for (int i = 0; i < 16; ++i)
        a += acc2[(size_t)(p0 + i) * 1024 + cx * 64 + ld];
    sA[w][ld] = a;
    if (cx == 0 && ld < 16) {
        float l = 0.f;
#pragma unroll
        for (int i = 0; i < 16; ++i) l += l2[(p0 + i) * 16 + ld];
        sLl[w][ld] = l;
    }
    __syncthreads();
    if (w == 0) {
        acc3[(size_t)g * 1024 + cx * 64 + ld] =
            sA[0][ld] + sA[1][ld] + sA[2][ld] + sA[3][ld];
        if (cx == 0 && ld < 16)
            l3g[g * 16 + ld] = sLl[0][ld] + sLl[1][ld] + sLl[2][ld] + sLl[3][ld];
    }
}

// Wo GEMV; prologue merges 8 group sums + divide.
// grid (4, 16), block 512 (8 waves, 2-way row split). blockIdx.y = head.
__global__ __launch_bounds__(512) void gemv_wo(
    const float* __restrict__ Wo,
    const float* __restrict__ l3g, const float* __restrict__ acc3,
    float* __restrict__ part) {
    __shared__ float vals[64];
    __shared__ float sred[2][256];
    int by = blockIdx.y;
    int t = threadIdx.x;
    if (t < 64) {
        float a = 0.f, L = 0.f;
#pragma unroll
        for (int g = 0; g < 8; ++g) {
            a += acc3[(size_t)g * 1024 + by * 64 + t];
            L += l3g[g * 16 + by];
        }
        vals[t] = a / L;
    }
    __syncthreads();
    int half = t >> 8, tc = t & 255;
    int col = blockIdx.x * 256 + tc;
    float acc = 0.f;
#pragma unroll 16
    for (int r = 0; r < 32; ++r)
        acc = fmaf(vals[half * 32 + r],
                   Wo[(size_t)(by * 64 + half * 32 + r) * EDIM + col], acc);
    sred[half][tc] = acc;
    __syncthreads();
    if (t < 256)
        part[(size_t)by * EDIM + blockIdx.x * 256 + t] = sred[0][t] + sred[1][t];
}

// W1 GEMV with fused residual+LN1 prologue. grid (4,16), block 512.
__global__ __launch_bounds__(512) void gemv_w1(
    const float* __restrict__ W1, const float* __restrict__ gp1,
    const float* __restrict__ bo, const float* __restrict__ x,
    const float* __restrict__ ln1s, const float* __restrict__ ln1b,
    float* __restrict__ h1, float* __restrict__ part) {
    __shared__ float r_l[1024];
    __shared__ float2 red[8];
    __shared__ float vals[64];
    __shared__ float sred[2][256];
    int t = threadIdx.x;
    float2 ss = {0.f, 0.f};
#pragma unroll
    for (int j = 0; j < 2; ++j) {
        int i = t + 512 * j;
        float v = x[i] + bo[i];
#pragma unroll
        for (int sl = 0; sl < 16; ++sl) v += gp1[(size_t)sl * EDIM + i];
        r_l[i] = v;
        ss.x += v; ss.y += v * v;
    }
    float2 s = blockSum512_2(ss, red);
    float mean = s.x * (1.f / 1024.f);
    float var = s.y * (1.f / 1024.f) - mean * mean;
    float rstd = rsqrtf(var + 1e-6f);
    int by = blockIdx.y;
    if (t < 64) {
        int row = by * 64 + t;
        float hv = (r_l[row] - mean) * rstd * ln1s[row] + ln1b[row];
        vals[t] = hv;
        if (blockIdx.x == 0) h1[row] = hv;
    }
    __syncthreads();
    int half = t >> 8, tc = t & 255;
    int col = blockIdx.x * 256 + tc;
    float acc = 0.f;
#pragma unroll 16
    for (int r = 0; r < 32; ++r)
        acc = fmaf(vals[half * 32 + r],
                   W1[(size_t)(by * 64 + half * 32 + r) * EDIM + col], acc);
    sred[half][tc] = acc;
    __syncthreads();
    if (t < 256)
        part[(size_t)by * EDIM + blockIdx.x * 256 + t] = sred[0][t] + sred[1][t];
}

// W2 GEMV with fused (bias + sum-partials + ReLU) prologue. grid (4,16), block 512.
__global__ __launch_bounds__(512) void gemv_w2(
    const float* __restrict__ W2, const float* __restrict__ gp2,
    const float* __restrict__ b1, float* __restrict__ part) {
    __shared__ float vals[64];
    __shared__ float sred[2][256];
    int by = blockIdx.y;
    int t = threadIdx.x;
    if (t < 64) {
        int r = by * 64 + t;
        float v = b1[r];
#pragma unroll
        for (int sl = 0; sl < 16; ++sl) v += gp2[(size_t)sl * EDIM + r];
        vals[t] = fmaxf(v, 0.f);
    }
    __syncthreads();
    int half = t >> 8, tc = t & 255;
    int col = blockIdx.x * 256 + tc;
    float acc = 0.f;
#pragma unroll 16
    for (int r = 0; r < 32; ++r)
        acc = fmaf(vals[half * 32 + r],
                   W2[(size_t)(by * 64 + half * 32 + r) * EDIM + col], acc);
    sred[half][tc] = acc;
    __syncthreads();
    if (t < 256)
        part[(size_t)by * EDIM + blockIdx.x * 256 + t] = sred[0][t] + sred[1][t];
}

// final LN: 1 block 1024. r = h1 + b2 + sum partials; out = LN(r)*g + b
__global__ __launch_bounds__(1024) void combine_ln(
    const float* __restrict__ part, const float* __restrict__ bias,
    const float* __restrict__ resid, const float* __restrict__ g,
    const float* __restrict__ b, float* __restrict__ out) {
    __shared__ float2 lds[16];
    int t = threadIdx.x;
    float v = bias[t];
#pragma unroll
    for (int sl = 0; sl < 16; ++sl) v += part[(size_t)sl * EDIM + t];
    float r = resid[t] + v;
    float2 s = blockSum1024_2((float2){r, r * r}, lds);
    float mean = s.x * (1.f / 1024.f);
    float var = s.y * (1.f / 1024.f) - mean * mean;
    out[t] = (r - mean) * rsqrtf(var + 1e-6f) * g[t] + b[t];
}

// ---------------- launch ----------------
extern "C" void kernel_launch(void* const* d_in, const int* in_sizes, int n_in,
                              void* d_out, int out_size, void* d_ws, size_t ws_size,
                              hipStream_t stream) {
    const float* x     = (const float*)d_in[0];
    const float* cache = (const float*)d_in[1];
    const float* Wv    = (const float*)d_in[2];
    const float* bv    = (const float*)d_in[3];
    const float* Wq    = (const float*)d_in[4];
    const float* bq    = (const float*)d_in[5];
    const float* Wk    = (const float*)d_in[6];
    const float* bk    = (const float*)d_in[7];
    const float* Wo    = (const float*)d_in[8];
    const float* bo    = (const float*)d_in[9];
    const float* W1    = (const float*)d_in[10];
    const float* b1    = (const float*)d_in[11];
    const float* W2    = (const float*)d_in[12];
    const float* b2    = (const float*)d_in[13];
    const float* ln1s  = (const float*)d_in[14];
    const float* ln1b  = (const float*)d_in[15];
    const float* ln2s  = (const float*)d_in[16];
    const float* ln2b  = (const float*)d_in[17];

    float* out = (float*)d_out;
    float* nv = out + 1024;
    float* nk = out + 1024 + (size_t)SLEN * EDIM;

    float* w     = (float*)d_ws;
    float* qkvp  = w;                           // 48*1024
    float* score = qkvp + 48 * 1024;            // 8192*16
    float* l2    = score + (size_t)SLEN * 16;   // NB2*16
    float* acc2  = l2 + (size_t)NB2 * 16;       // NB2*1024
    float* l3g   = acc2 + (size_t)NB2 * 1024;   // 128
    float* acc3  = l3g + 128;                   // 8*1024
    float* gp1   = acc3 + 8 * 1024;             // 16*1024
    float* h1    = gp1 + 16 * 1024;             // 1024
    float* gp2   = h1 + 1024;                   // 16*1024
    float* gp3   = gp2 + 16 * 1024;             // 16*1024

    qkv_partial<<<dim3(12, 16), 256, 0, stream>>>(Wq, Wk, Wv, x, qkvp);
    attn_copyK<<<512, 512, 0, stream>>>(cache, qkvp, bq, bk, nk, score);
    attn_copyV<<<NB2, 512, 0, stream>>>(cache, qkvp, bv, score, nv, l2, acc2);
    attn_red<<<dim3(16, 8), 256, 0, stream>>>(l2, acc2, l3g, acc3);
    gemv_wo<<<dim3(4, 16), 512, 0, stream>>>(Wo, l3g, acc3, gp1);
    gemv_w1<<<dim3(4, 16), 512, 0, stream>>>(W1, gp1, bo, x, ln1s, ln1b, h1, gp2);
    gemv_w2<<<dim3(4, 16), 512, 0, stream>>>(W2, gp2, b1, gp3);
    combine_ln<<<1, 1024, 0, stream>>>(gp3, b2, h1, ln2s, ln2b, out);
}